// Round 1
// baseline (711.969 us; speedup 1.0000x reference)
//
#include <hip/hip_runtime.h>

// Problem constants (reference: T=500, B=1024, N=256, alpha=0.995, v_th=1)
#define T_STEPS 500
#define BATCH   1024
#define NDIM    256
#define ALPHA_F 0.995f

// Kernel 1: s[r] = dot(x[r*256 .. +255], w) for r in [0, T*B)
// One wave (64 lanes) per row; each lane loads a float4 (coalesced 1KB/wave).
__global__ __launch_bounds__(256) void lif_dot_kernel(
    const float* __restrict__ x, const float* __restrict__ w,
    float* __restrict__ s, int rows)
{
    int gtid = blockIdx.x * blockDim.x + threadIdx.x;
    int row  = gtid >> 6;
    int lane = threadIdx.x & 63;
    if (row >= rows) return;

    const float4 xv = *(const float4*)(x + (size_t)row * NDIM + lane * 4);
    const float4 wv = *(const float4*)(w + lane * 4);

    float p = xv.x * wv.x + xv.y * wv.y + xv.z * wv.z + xv.w * wv.w;

    // 64-lane butterfly reduction
    p += __shfl_xor(p, 32, 64);
    p += __shfl_xor(p, 16, 64);
    p += __shfl_xor(p, 8, 64);
    p += __shfl_xor(p, 4, 64);
    p += __shfl_xor(p, 2, 64);
    p += __shfl_xor(p, 1, 64);

    if (lane == 0) s[row] = p;
}

// Kernel 2: per-batch sequential LIF scan over T.
// sz buffer initially holds s[t*B+b]; we overwrite it with z[t*B+b] (same
// thread reads index before writing it, reads always run ahead of writes).
__global__ __launch_bounds__(64) void lif_scan_kernel(
    float* __restrict__ vout, float* __restrict__ sz)
{
    int b = blockIdx.x * 64 + threadIdx.x;   // 16 blocks x 64 = 1024 threads
    if (b >= BATCH) return;

    float v = 0.0f, z = 0.0f;

    float cur[4];
#pragma unroll
    for (int j = 0; j < 4; ++j) cur[j] = sz[(size_t)j * BATCH + b];

    for (int t0 = 0; t0 < T_STEPS; t0 += 4) {
        float nxt[4] = {0.f, 0.f, 0.f, 0.f};
        if (t0 + 4 < T_STEPS) {
#pragma unroll
            for (int j = 0; j < 4; ++j)
                nxt[j] = sz[(size_t)(t0 + 4 + j) * BATCH + b];
        }
#pragma unroll
        for (int j = 0; j < 4; ++j) {
            float sv = cur[j];
            v = (ALPHA_F * v + sv) - z;          // v_th = 1
            z = (v - 1.0f > 0.0f) ? 1.0f : 0.0f;
            vout[(size_t)(t0 + j) * BATCH + b] = v;
            sz  [(size_t)(t0 + j) * BATCH + b] = z;
        }
#pragma unroll
        for (int j = 0; j < 4; ++j) cur[j] = nxt[j];
    }
}

extern "C" void kernel_launch(void* const* d_in, const int* in_sizes, int n_in,
                              void* d_out, int out_size, void* d_ws, size_t ws_size,
                              hipStream_t stream)
{
    const float* x = (const float*)d_in[0];   // [T, B, N] f32
    const float* w = (const float*)d_in[1];   // [N] f32
    float* out = (float*)d_out;               // [v_seq (T*B) | z_seq (T*B)] f32

    float* vout = out;                        // v_seq
    float* sz   = out + (size_t)T_STEPS * BATCH;  // scratch for s, then z_seq

    const int rows = T_STEPS * BATCH;         // 512000 dot products
    const int waves_per_block = 4;            // 256 threads
    const int blocks = (rows + waves_per_block - 1) / waves_per_block;

    lif_dot_kernel<<<blocks, 256, 0, stream>>>(x, w, sz, rows);
    lif_scan_kernel<<<BATCH / 64, 64, 0, stream>>>(vout, sz);
}